// Round 2
// baseline (45.541 us; speedup 1.0000x reference)
//
#include <hip/hip_runtime.h>

// CenterlineLoss — symmetric masked chamfer distance, dot-product form.
// d^2(q,k) = |q|^2 + (|k|^2 - 2 q.k); inner loop = 2 fma + 0.5 min3 per pair.

constexpr int NP = 16384;          // proj points
constexpr int NR = 8192;           // ref points
constexpr int CH = 256;            // key-chunk length (both directions)
constexpr int S1 = NR / CH;        // 32 chunks of ref  (dir1: per-proj min)
constexpr int S2 = NP / CH;        // 64 chunks of proj (dir2: per-ref min)
constexpr int BLK1 = NP / 1024;    // 16 point-blocks (1024 queries per block)
constexpr int BLK2 = NR / 1024;    // 8
constexpr int G1 = BLK1 * S1;      // 512 blocks dir1
constexpr int G2 = BLK2 * S2;      // 512 blocks dir2
constexpr float FMAX = 3.4e38f;

// ---- K0: precompute key triples (-2k0, -2k1, |k|^2, pad) ----
// kref keys are pre-swapped so they pair with raw proj (p0,p1).
// kproj keys carry the in-bounds mask as a 1e30 sentinel in .z.
__global__ __launch_bounds__(256) void k_prep(const float* __restrict__ proj,
                                              const float* __restrict__ ref,
                                              float4* __restrict__ kproj,
                                              float4* __restrict__ kref) {
    int i = blockIdx.x * 256 + threadIdx.x;
    float2 p = ((const float2*)proj)[i];
    bool valid = (p.x >= 0.f) && (p.x <= 640.f) && (p.y >= 0.f) && (p.y <= 480.f);
    float pc = fmaf(p.x, p.x, p.y * p.y);
    kproj[i] = valid ? make_float4(-2.f * p.x, -2.f * p.y, pc, 0.f)
                     : make_float4(0.f, 0.f, 1e30f, 0.f);
    if (i < NR) {
        float2 r = ((const float2*)ref)[i];
        // swapped ref r' = (r.y, r.x) pairs with q = (p0, p1)
        kref[i] = make_float4(-2.f * r.y, -2.f * r.x, fmaf(r.x, r.x, r.y * r.y), 0.f);
    }
}

// ---- K1: fused pairwise partial-min, both directions ----
// blocks [0,G1): dir1 — queries = proj (raw), keys = kref chunk
// blocks [G1,G1+G2): dir2 — queries = ref (swapped), keys = kproj chunk
__global__ __launch_bounds__(256) void k_pair(const float* __restrict__ proj,
                                              const float* __restrict__ ref,
                                              const float4* __restrict__ kproj,
                                              const float4* __restrict__ kref,
                                              float* __restrict__ part1,
                                              float* __restrict__ part2) {
    __shared__ float4 sh[CH];
    int tid = threadIdx.x;
    int bx = blockIdx.x;
    bool d1 = bx < G1;
    int cb = d1 ? bx : bx - G1;
    int nbm = (d1 ? BLK1 : BLK2) - 1;
    int pb = cb & nbm;                     // query-block index
    int ck = cb >> (d1 ? 4 : 3);           // key-chunk index

    const float4* keys = d1 ? kref : kproj;
    sh[tid] = keys[ck * CH + tid];
    __syncthreads();

    int base = pb * 1024 + tid;
    const float2* qsrc = (const float2*)(d1 ? proj : ref);
    float2 q0 = qsrc[base];
    float2 q1 = qsrc[base + 256];
    float2 q2 = qsrc[base + 512];
    float2 q3 = qsrc[base + 768];
    if (!d1) {  // ref columns swapped
        float t;
        t = q0.x; q0.x = q0.y; q0.y = t;
        t = q1.x; q1.x = q1.y; q1.y = t;
        t = q2.x; q2.x = q2.y; q2.y = t;
        t = q3.x; q3.x = q3.y; q3.y = t;
    }

    float ma0 = FMAX, mb0 = FMAX, ma1 = FMAX, mb1 = FMAX;
    float ma2 = FMAX, mb2 = FMAX, ma3 = FMAX, mb3 = FMAX;
#pragma unroll 4
    for (int j = 0; j < CH; j += 4) {
        float4 k0 = sh[j], k1 = sh[j + 1], k2 = sh[j + 2], k3 = sh[j + 3];
        float t00 = fmaf(k0.y, q0.y, fmaf(k0.x, q0.x, k0.z));
        float t01 = fmaf(k1.y, q0.y, fmaf(k1.x, q0.x, k1.z));
        float t02 = fmaf(k2.y, q0.y, fmaf(k2.x, q0.x, k2.z));
        float t03 = fmaf(k3.y, q0.y, fmaf(k3.x, q0.x, k3.z));
        ma0 = fminf(fminf(ma0, t00), t01);
        mb0 = fminf(fminf(mb0, t02), t03);
        float t10 = fmaf(k0.y, q1.y, fmaf(k0.x, q1.x, k0.z));
        float t11 = fmaf(k1.y, q1.y, fmaf(k1.x, q1.x, k1.z));
        float t12 = fmaf(k2.y, q1.y, fmaf(k2.x, q1.x, k2.z));
        float t13 = fmaf(k3.y, q1.y, fmaf(k3.x, q1.x, k3.z));
        ma1 = fminf(fminf(ma1, t10), t11);
        mb1 = fminf(fminf(mb1, t12), t13);
        float t20 = fmaf(k0.y, q2.y, fmaf(k0.x, q2.x, k0.z));
        float t21 = fmaf(k1.y, q2.y, fmaf(k1.x, q2.x, k1.z));
        float t22 = fmaf(k2.y, q2.y, fmaf(k2.x, q2.x, k2.z));
        float t23 = fmaf(k3.y, q2.y, fmaf(k3.x, q2.x, k3.z));
        ma2 = fminf(fminf(ma2, t20), t21);
        mb2 = fminf(fminf(mb2, t22), t23);
        float t30 = fmaf(k0.y, q3.y, fmaf(k0.x, q3.x, k0.z));
        float t31 = fmaf(k1.y, q3.y, fmaf(k1.x, q3.x, k1.z));
        float t32 = fmaf(k2.y, q3.y, fmaf(k2.x, q3.x, k2.z));
        float t33 = fmaf(k3.y, q3.y, fmaf(k3.x, q3.x, k3.z));
        ma3 = fminf(fminf(ma3, t30), t31);
        mb3 = fminf(fminf(mb3, t32), t33);
    }

    float* part = d1 ? part1 : part2;
    int n = d1 ? NP : NR;
    part[ck * n + base]       = fminf(ma0, mb0);
    part[ck * n + base + 256] = fminf(ma1, mb1);
    part[ck * n + base + 512] = fminf(ma2, mb2);
    part[ck * n + base + 768] = fminf(ma3, mb3);
}

// ---- K2: combine — min over chunks, +|q|^2, sqrt, masked block sums ----
__global__ __launch_bounds__(256) void k_combine(const float* __restrict__ proj,
                                                 const float* __restrict__ ref,
                                                 const float* __restrict__ part1,
                                                 const float* __restrict__ part2,
                                                 float* __restrict__ bsum1,
                                                 float* __restrict__ bcnt1,
                                                 float* __restrict__ bsum2) {
    __shared__ float red[256];
    __shared__ float redc[256];
    int tid = threadIdx.x;
    int b = blockIdx.x;
    if (b < 64) {
        int i = b * 256 + tid;
        float m = FMAX;
        for (int c = 0; c < S1; ++c) m = fminf(m, part1[c * NP + i]);
        float2 p = ((const float2*)proj)[i];
        bool valid = (p.x >= 0.f) && (p.x <= 640.f) && (p.y >= 0.f) && (p.y <= 480.f);
        float d = sqrtf(fmaxf(m + fmaf(p.x, p.x, p.y * p.y), 0.f));
        red[tid]  = valid ? d : 0.f;
        redc[tid] = valid ? 1.f : 0.f;
        __syncthreads();
        for (int w = 128; w > 0; w >>= 1) {
            if (tid < w) { red[tid] += red[tid + w]; redc[tid] += redc[tid + w]; }
            __syncthreads();
        }
        if (tid == 0) { bsum1[b] = red[0]; bcnt1[b] = redc[0]; }
    } else {
        int j = (b - 64) * 256 + tid;
        float m = FMAX;
        for (int c = 0; c < S2; ++c) m = fminf(m, part2[c * NR + j]);
        float2 r = ((const float2*)ref)[j];
        red[tid] = sqrtf(fmaxf(m + fmaf(r.x, r.x, r.y * r.y), 0.f));
        __syncthreads();
        for (int w = 128; w > 0; w >>= 1) {
            if (tid < w) red[tid] += red[tid + w];
            __syncthreads();
        }
        if (tid == 0) bsum2[b - 64] = red[0];
    }
}

// ---- K3: final scalar, fixed order ----
__global__ void k_final(const float* __restrict__ bsum1,
                        const float* __restrict__ bcnt1,
                        const float* __restrict__ bsum2,
                        float* __restrict__ out) {
    float s1 = 0.f, c1 = 0.f, s2 = 0.f;
    for (int b = 0; b < 64; ++b) { s1 += bsum1[b]; c1 += bcnt1[b]; }
    for (int b = 0; b < 32; ++b) s2 += bsum2[b];
    out[0] = 0.5f * (s1 / c1 + s2 / (float)NR);
}

extern "C" void kernel_launch(void* const* d_in, const int* in_sizes, int n_in,
                              void* d_out, int out_size, void* d_ws, size_t ws_size,
                              hipStream_t stream) {
    const float* proj = (const float*)d_in[0];   // 16384 x 2
    const float* ref  = (const float*)d_in[1];   // 8192 x 2
    float* out = (float*)d_out;

    float* ws = (float*)d_ws;
    float4* kproj = (float4*)ws;                       // 16384 float4
    float4* kref  = kproj + NP;                        // 8192 float4
    float*  part1 = (float*)(kref + NR);               // S1*NP = 524288
    float*  part2 = part1 + S1 * NP;                   // S2*NR = 524288
    float*  bsum1 = part2 + S2 * NR;                   // 64
    float*  bcnt1 = bsum1 + 64;                        // 64
    float*  bsum2 = bcnt1 + 64;                        // 32

    k_prep<<<NP / 256, 256, 0, stream>>>(proj, ref, kproj, kref);
    k_pair<<<G1 + G2, 256, 0, stream>>>(proj, ref, kproj, kref, part1, part2);
    k_combine<<<96, 256, 0, stream>>>(proj, ref, part1, part2, bsum1, bcnt1, bsum2);
    k_final<<<1, 1, 0, stream>>>(bsum1, bcnt1, bsum2, out);
}